// Round 10
// baseline (247.887 us; speedup 1.0000x reference)
//
#include <hip/hip_runtime.h>
#include <hip/hip_bf16.h>
#include <math.h>

#define NTOK 8192
#define HID  1024
#define ISZ  256
#define NEXP 16
#define NBIG 4096  // NEXP*ISZ

typedef __attribute__((ext_vector_type(8))) short bf16x8;
typedef __attribute__((ext_vector_type(4))) float f32x4;

#define MFMA16(a, b, c) __builtin_amdgcn_mfma_f32_16x16x32_bf16(a, b, c, 0, 0, 0)

__device__ __forceinline__ unsigned short f2bf(float f) {
  unsigned u = __float_as_uint(f);
  u += 0x7fff + ((u >> 16) & 1);
  return (unsigned short)(u >> 16);
}

__device__ __forceinline__ void async16(void* l, const void* g) {
  __builtin_amdgcn_global_load_lds(
      (const __attribute__((address_space(1))) unsigned int*)g,
      (__attribute__((address_space(3))) unsigned int*)l, 16, 0, 0);
}

// ---------------- sim_matrix column inverse norms ----------------
__global__ void simnorm_kernel(const float* __restrict__ sm, float* __restrict__ inv_smn) {
  __shared__ float red[16][17];
  int t = threadIdx.x;
  int e = t & 15, g = t >> 4;
  float ss = 0.f;
  for (int c = g; c < HID; c += 16) {
    float v = sm[c * NEXP + e];
    ss += v * v;
  }
  red[e][g] = ss;
  __syncthreads();
  if (t < 16) {
    float s = 0.f;
    #pragma unroll
    for (int i = 0; i < 16; i++) s += red[t][i];
    inv_smn[t] = 1.f / fmaxf(sqrtf(s), 1e-12f);
  }
}

// ---------------- gate: scores, k, routing weights, bf16 cast of x ----------------
__global__ __launch_bounds__(256)
void gate_kernel(const float* __restrict__ x, const float* __restrict__ sm,
                 const float* __restrict__ thr, const float* __restrict__ inv_smn,
                 float* __restrict__ scores_out, float* __restrict__ k_out,
                 float* __restrict__ rw_out, unsigned short* __restrict__ xb_out) {
  const int n = blockIdx.x;
  const int t = threadIdx.x;
  const int lane = t & 63, wave = t >> 6;
  const float* xr = x + (size_t)n * HID;

  float p[16];
  #pragma unroll
  for (int e = 0; e < 16; e++) p[e] = 0.f;
  float ss = 0.f;

  #pragma unroll
  for (int q = 0; q < 4; q++) {
    int c = t + q * 256;
    float v = xr[c];
    ss += v * v;
    xb_out[(size_t)n * HID + c] = f2bf(v);
    const float4* smr = (const float4*)(sm + (size_t)c * NEXP);
    float4 s0 = smr[0], s1 = smr[1], s2 = smr[2], s3 = smr[3];
    p[0] += v * s0.x;  p[1] += v * s0.y;  p[2] += v * s0.z;  p[3] += v * s0.w;
    p[4] += v * s1.x;  p[5] += v * s1.y;  p[6] += v * s1.z;  p[7] += v * s1.w;
    p[8] += v * s2.x;  p[9] += v * s2.y;  p[10] += v * s2.z; p[11] += v * s2.w;
    p[12] += v * s3.x; p[13] += v * s3.y; p[14] += v * s3.z; p[15] += v * s3.w;
  }

  #pragma unroll
  for (int off = 32; off > 0; off >>= 1) {
    ss += __shfl_down(ss, off, 64);
    #pragma unroll
    for (int e = 0; e < 16; e++) p[e] += __shfl_down(p[e], off, 64);
  }

  __shared__ float red[4][17];
  __shared__ float sc[16];
  if (lane == 0) {
    red[wave][0] = ss;
    #pragma unroll
    for (int e = 0; e < 16; e++) red[wave][1 + e] = p[e];
  }
  __syncthreads();

  if (t < 16) {
    float d = red[0][1 + t] + red[1][1 + t] + red[2][1 + t] + red[3][1 + t];
    float ssum = red[0][0] + red[1][0] + red[2][0] + red[3][0];
    float inv_x = 1.f / fmaxf(sqrtf(ssum), 1e-12f);
    float s = d * inv_x * inv_smn[t];
    scores_out[(size_t)n * 16 + t] = s;
    sc[t] = s;
  }
  __syncthreads();

  if (t < 16) {
    float thrv = thr[0];
    float s = sc[t];
    bool act = s > thrv;
    float m = act ? s : -INFINITY;
    int cnt = act ? 1 : 0;
    #pragma unroll
    for (int off = 8; off > 0; off >>= 1) {
      m = fmaxf(m, __shfl_xor(m, off, 16));
      cnt += __shfl_xor(cnt, off, 16);
    }
    float pv;
    if (cnt > 0) pv = act ? expf(s - m) : 0.f;
    else         pv = 1.f;
    float sum = pv;
    #pragma unroll
    for (int off = 8; off > 0; off >>= 1) sum += __shfl_xor(sum, off, 16);
    rw_out[(size_t)n * 16 + t] = pv / sum;
    if (t == 0) k_out[n] = (float)cnt;
  }
}

// ---------------- transpose + bf16 cast (per-expert 2D transpose) ----------------
__global__ __launch_bounds__(256)
void transpose_cast_kernel(const float* __restrict__ src, unsigned short* __restrict__ dst,
                           int R, int C, int dstride, int e_src_stride, int e_dst_mult) {
  __shared__ float tile[32][33];
  const int e = blockIdx.z;
  const int r0 = blockIdx.y * 32, c0 = blockIdx.x * 32;
  const int tx = threadIdx.x & 31, ty = threadIdx.x >> 5;
  const float* s = src + (size_t)e * e_src_stride;
  #pragma unroll
  for (int q = 0; q < 4; q++) {
    int r = r0 + ty + q * 8;
    tile[ty + q * 8][tx] = s[(size_t)r * C + c0 + tx];
  }
  __syncthreads();
  unsigned short* d = dst + (size_t)e * e_dst_mult;
  #pragma unroll
  for (int q = 0; q < 4; q++) {
    int cc = c0 + ty + q * 8;
    int r  = r0 + tx;
    d[(size_t)cc * dstride + r] = f2bf(tile[tx][ty + q * 8]);
  }
}

// ========== GEMM1: 256x256, 8 waves, A via LDS, B DIRECT from global/L2 ==========
// B-frag for mfma_16x16x32 = 16 contiguous bytes of B^T row -> plain global
// load into VGPR (no LDS round-trip, no barrier coupling; reg ping-pong b0/b1).
// A: async16-staged, dbuf 2x32KB, swizzle (r&7)<<4. One manual vmcnt(8)/tile
// retires exactly the 4 A-stages (A issued before B, sched_barrier-pinned);
// compiler auto-waits track the B regs.
#define G1_LOADB(dst, kt)                                                       \
  _Pragma("unroll")                                                             \
  for (int nl = 0; nl < 4; nl++) {                                              \
    _Pragma("unroll")                                                           \
    for (int h = 0; h < 2; h++)                                                 \
      dst[nl][h] = *(const bf16x8*)(Bg2 + (size_t)(kt) * 128 + nl * (LD * 32) + h * 64); \
  }

#define G1_COMPUTE(bufA, bb)                                                    \
  _Pragma("unroll")                                                             \
  for (int kk = 0; kk < 2; kk++) {                                              \
    const int ck = kk ? colk1 : colk0;                                          \
    bf16x8 a[8];                                                                \
    _Pragma("unroll")                                                           \
    for (int mf = 0; mf < 8; mf++)                                              \
      a[mf] = *(const bf16x8*)((bufA) + wmo + mf * 2048 + lro + ck);            \
    _Pragma("unroll")                                                           \
    for (int mf = 0; mf < 8; mf++)                                              \
      _Pragma("unroll")                                                         \
      for (int nf = 0; nf < 4; nf++)                                            \
        acc[mf][nf] = MFMA16(a[mf], bb[nf][kk], acc[mf][nf]);                   \
  }

template <int KEXT, int LD, int NBN>
__global__ __launch_bounds__(512, 2)
void gemm1_bd(const unsigned short* __restrict__ A, const unsigned short* __restrict__ B,
              unsigned short* __restrict__ Cb, const float* __restrict__ rw) {
  __shared__ __align__(1024) char lds[65536];
  constexpr int NT = KEXT / 64;
  const int tid = threadIdx.x;
  const int lane = tid & 63, wid = tid >> 6;
  const int wm = wid >> 2, wn = wid & 3;   // 2 x 4 waves, wave tile 128x64
  const int lr = lane & 15;

  const int nwg = gridDim.x, cpx = nwg >> 3;
  const int wg = (blockIdx.x & 7) * cpx + (blockIdx.x >> 3);
  const int bm = wg / NBN, bn = wg % NBN;

  const int swz = (lr & 7) << 4;
  const int colk0 = ((lane >> 4) * 16) ^ swz;
  const int colk1 = (64 + (lane >> 4) * 16) ^ swz;
  const int wmo = wm * 16384, lro = lr * 128;  // A region [256r][128B]

  // A staging decode (4 units of 512thr x 16B; linear dest, inv-swizzled src)
  int sRow[4], sCol[4], so[4];
  #pragma unroll
  for (int i = 0; i < 4; i++) {
    int o = (i * 512 + tid) * 16;
    so[i] = o;
    int r = o >> 7, cb = o & 127;
    sRow[i] = r; sCol[i] = (cb ^ ((r & 7) << 4)) >> 1;
  }

  const unsigned short* Ag = A + (size_t)bm * 256 * LD;
  // per-thread B fragment base: row = bn*256 + wn*64 + lr, kgroup = (lane>>4)*8
  const char* Bg2 = (const char*)(B + (size_t)(bn * 256 + wn * 64 + lr) * LD) + ((lane >> 4) * 16);

  f32x4 acc[8][4];
  #pragma unroll
  for (int m = 0; m < 8; m++)
    #pragma unroll
    for (int n = 0; n < 4; n++) acc[m][n] = (f32x4){0.f, 0.f, 0.f, 0.f};

  bf16x8 b0[4][2], b1[4][2];

  // prologue: stage A(0) -> buf0; load B(0) -> b0; retire A only (vmcnt(8))
  #pragma unroll
  for (int i = 0; i < 4; i++) async16(lds + so[i], Ag + (size_t)sRow[i] * LD + sCol[i]);
  __builtin_amdgcn_sched_barrier(0);
  G1_LOADB(b0, 0)
  __builtin_amdgcn_sched_barrier(0);
  asm volatile("s_waitcnt vmcnt(8)" ::: "memory");
  __builtin_amdgcn_s_barrier();
  __builtin_amdgcn_sched_barrier(0);

  #pragma unroll 1
  for (int t = 0; t < NT; t += 2) {
    {
      const int kn = (t + 1) & (NT - 1);
      #pragma unroll
      for (int i = 0; i < 4; i++)
        async16(lds + 32768 + so[i], Ag + (size_t)sRow[i] * LD + kn * 64 + sCol[i]);
      __builtin_amdgcn_sched_barrier(0);
      G1_LOADB(b1, kn)
      __builtin_amdgcn_sched_barrier(0);
      G1_COMPUTE(lds, b0)
      __builtin_amdgcn_sched_barrier(0);
      asm volatile("s_waitcnt vmcnt(8)" ::: "memory");
      __builtin_amdgcn_s_barrier();
      __builtin_amdgcn_sched_barrier(0);
    }
    {
      const int kn = (t + 2) & (NT - 1);
      #pragma unroll
      for (int i = 0; i < 4; i++)
        async16(lds + so[i], Ag + (size_t)sRow[i] * LD + kn * 64 + sCol[i]);
      __builtin_amdgcn_sched_barrier(0);
      G1_LOADB(b0, kn)
      __builtin_amdgcn_sched_barrier(0);
      G1_COMPUTE(lds + 32768, b1)
      __builtin_amdgcn_sched_barrier(0);
      asm volatile("s_waitcnt vmcnt(8)" ::: "memory");
      __builtin_amdgcn_s_barrier();
      __builtin_amdgcn_sched_barrier(0);
    }
  }

  asm volatile("s_waitcnt vmcnt(0)" ::: "memory");

  // epilogue: C/D layout col=lane&15, row=(lane>>4)*4+j (verified)
  const int jr = (lane >> 4) * 4;
  float wrow[8][4];
  #pragma unroll
  for (int m = 0; m < 8; m++)
    #pragma unroll
    for (int j = 0; j < 4; j++)
      wrow[m][j] = rw[(size_t)(bm * 256 + wm * 128 + m * 16 + jr + j) * 16 + bn];
  #pragma unroll
  for (int m = 0; m < 8; m++) {
    #pragma unroll
    for (int n = 0; n < 4; n++) {
      int col = bn * 256 + wn * 64 + n * 16 + lr;
      #pragma unroll
      for (int j = 0; j < 4; j++) {
        int r = bm * 256 + wm * 128 + m * 16 + jr + j;
        float v = acc[m][n][j];
        float g = 0.7978845608f * (v + 0.044715f * v * v * v);
        float e = __expf(2.f * g);
        float th = 1.f - 2.f / (e + 1.f);   // tanh(g), inf-safe
        float ge = 0.5f * v * (1.f + th);
        Cb[(size_t)r * NBIG + col] = f2bf(ge * wrow[m][j]);
      }
    }
  }
}

// ============ GEMM2: 128x256, 8-wave (2x4), 2-phase/K-tile (r6-verified) ============
#define G2PHASE(CK, STG, WAIT_)                                                \
  {                                                                            \
    bf16x8 afr[4], bfr[4];                                                     \
    _Pragma("unroll")                                                          \
    for (int ml = 0; ml < 4; ml++)                                             \
      afr[ml] = *(const bf16x8*)(bufA + wmo + ml*2048 + lro + (CK));           \
    _Pragma("unroll")                                                          \
    for (int nl = 0; nl < 4; nl++)                                             \
      bfr[nl] = *(const bf16x8*)(bufB + wno + nl*2048 + lro + (CK));           \
    if (STG) {                                                                 \
      _Pragma("unroll")                                                        \
      for (int i = 0; i < 2; i++)                                              \
        async16(ldsAn + o16[i], Ag + (size_t)aRow[i]*K + kn + aCol[i]);        \
      _Pragma("unroll")                                                        \
      for (int i = 0; i < 4; i++)                                              \
        async16(ldsBn + o16b[i], Bg + (size_t)bRow[i]*K + kn + bCol[i]);       \
    }                                                                          \
    __builtin_amdgcn_sched_barrier(0);                                         \
    __builtin_amdgcn_s_barrier();                                              \
    asm volatile("s_waitcnt lgkmcnt(0)" ::: "memory");                         \
    __builtin_amdgcn_sched_barrier(0);                                         \
    __builtin_amdgcn_s_setprio(1);                                             \
    _Pragma("unroll")                                                          \
    for (int m4 = 0; m4 < 4; m4++)                                             \
      _Pragma("unroll")                                                        \
      for (int n4 = 0; n4 < 4; n4++)                                           \
        acc[m4][n4] = MFMA16(afr[m4], bfr[n4], acc[m4][n4]);                   \
    __builtin_amdgcn_s_setprio(0);                                             \
    __builtin_amdgcn_sched_barrier(0);                                         \
    if (WAIT_) { asm volatile("s_waitcnt vmcnt(0)" ::: "memory"); }            \
    __builtin_amdgcn_s_barrier();                                              \
    __builtin_amdgcn_sched_barrier(0);                                         \
  }

template <int K>
__global__ __launch_bounds__(512, 2)
void gemm2_k(const unsigned short* __restrict__ A, const unsigned short* __restrict__ B,
             float* __restrict__ Cf) {
  __shared__ __align__(1024) char lds[98304];
  constexpr int NT = K / 64;
  const int tid = threadIdx.x;
  const int lane = tid & 63, wid = tid >> 6;
  const int wm = wid >> 2, wn = wid & 3;   // 2 x 4 waves, wave tile 64x64
  const int lr = lane & 15;

  const int wg = (blockIdx.x & 7) * 32 + (blockIdx.x >> 3);  // nwg=256
  const int bm = wg >> 2, bn = wg & 3;

  const int swz = (lr & 7) << 4;
  const int colk0 = ((lane >> 4) * 16) ^ swz;
  const int colk1 = (64 + (lane >> 4) * 16) ^ swz;
  const int wmo = wm * 8192, wno = wn * 8192, lro = lr * 128;

  int aRow[2], aCol[2], o16[2];
  int bRow[4], bCol[4], o16b[4];
  #pragma unroll
  for (int i = 0; i < 2; i++) {
    int o = (i * 512 + tid) * 16;
    o16[i] = o;
    int r = o >> 7, cb = o & 127;
    aRow[i] = r; aCol[i] = (cb ^ ((r & 7) << 4)) >> 1;
  }
  #pragma unroll
  for (int i = 0; i < 4; i++) {
    int o = (i * 512 + tid) * 16;
    o16b[i] = o;
    int r = o >> 7, cb = o & 127;
    bRow[i] = r; bCol[i] = (cb ^ ((r & 7) << 4)) >> 1;
  }

  const unsigned short* Ag = A + (size_t)bm * 128 * K;
  const unsigned short* Bg = B + (size_t)bn * 256 * K;

  f32x4 acc[4][4];
  #pragma unroll
  for (int m = 0; m < 4; m++)
    #pragma unroll
    for (int n = 0; n < 4; n++) acc[m][n] = (f32x4){0.f, 0.f, 0.f, 0.f};

  #pragma unroll
  for (int i = 0; i < 2; i++) async16(lds + o16[i],          Ag + (size_t)aRow[i] * K + aCol[i]);
  #pragma unroll
  for (int i = 0; i < 4; i++) async16(lds + 32768 + o16b[i], Bg + (size_t)bRow[i] * K + bCol[i]);
  asm volatile("s_waitcnt vmcnt(0)" ::: "memory");
  __builtin_amdgcn_s_barrier();

  #pragma unroll 1
  for (int t = 0; t < NT; t += 2) {
    {
      const char* bufA = lds;
      const char* bufB = lds + 32768;
      char* ldsAn = lds + 16384;
      char* ldsBn = lds + 32768 + 32768;
      const int kn = ((t + 1) & (NT - 1)) << 6;
      G2PHASE(colk0, 1, 0)
      G2PHASE(colk1, 0, 1)
    }
    {
      const char* bufA = lds + 16384;
      const char* bufB = lds + 32768 + 32768;
      char* ldsAn = lds;
      char* ldsBn = lds + 32768;
      const int kn = ((t + 2) & (NT - 1)) << 6;
      G2PHASE(colk0, 1, 0)
      G2PHASE(colk1, 0, 1)
    }
  }

  asm volatile("s_waitcnt vmcnt(0)" ::: "memory");

  const int jr = (lane >> 4) * 4;
  #pragma unroll
  for (int m = 0; m < 4; m++) {
    #pragma unroll
    for (int n = 0; n < 4; n++) {
      int col = bn * 256 + wn * 64 + n * 16 + lr;
      #pragma unroll
      for (int j = 0; j < 4; j++) {
        int r = bm * 128 + wm * 64 + m * 16 + jr + j;
        Cf[(size_t)r * HID + col] = acc[m][n][j];
      }
    }
  }
}

extern "C" void kernel_launch(void* const* d_in, const int* in_sizes, int n_in,
                              void* d_out, int out_size, void* d_ws, size_t ws_size,
                              hipStream_t stream) {
  const float* x   = (const float*)d_in[0];
  const float* sm  = (const float*)d_in[1];
  const float* thr = (const float*)d_in[2];
  const float* w1  = (const float*)d_in[3];
  const float* w2  = (const float*)d_in[4];

  float* out_final  = (float*)d_out;
  float* out_scores = out_final + (size_t)NTOK * HID;
  float* out_k      = out_scores + (size_t)NTOK * NEXP;

  char* ws = (char*)d_ws;
  size_t off = 0;
  float* inv_smn = (float*)(ws + off); off += 256;
  float* rwbuf   = (float*)(ws + off); off += (size_t)NTOK * NEXP * 4;
  unsigned short* Xb  = (unsigned short*)(ws + off); off += (size_t)NTOK * HID * 2;
  unsigned short* W1T = (unsigned short*)(ws + off); off += (size_t)NBIG * HID * 2;
  unsigned short* W2T = (unsigned short*)(ws + off); off += (size_t)HID * NBIG * 2;
  unsigned short* H   = (unsigned short*)(ws + off); off += (size_t)NTOK * NBIG * 2;

  simnorm_kernel<<<1, 256, 0, stream>>>(sm, inv_smn);
  gate_kernel<<<NTOK, 256, 0, stream>>>(x, sm, thr, inv_smn, out_scores, out_k, rwbuf, Xb);
  transpose_cast_kernel<<<dim3(ISZ / 32, HID / 32, NEXP), 256, 0, stream>>>(
      w1, W1T, HID, ISZ, HID, HID * ISZ, ISZ * HID);
  transpose_cast_kernel<<<dim3(HID / 32, ISZ / 32, NEXP), 256, 0, stream>>>(
      w2, W2T, ISZ, HID, NBIG, ISZ * HID, ISZ);

  // H = gelu(Xb @ W1T^T) * rw   [8192 x 4096], 512 blocks (B-direct experiment)
  gemm1_bd<HID, HID, 16><<<512, 512, 0, stream>>>(Xb, W1T, H, rwbuf);
  // final = H @ W2T^T            [8192 x 1024], 256 blocks (r6-verified)
  gemm2_k<NBIG><<<256, 512, 0, stream>>>(H, W2T, out_final);
}

// Round 11
// 229.687 us; speedup vs baseline: 1.0792x; 1.0792x over previous
//
#include <hip/hip_runtime.h>
#include <hip/hip_bf16.h>
#include <math.h>

#define NTOK 8192
#define HID  1024
#define ISZ  256
#define NEXP 16
#define NBIG 4096  // NEXP*ISZ

typedef __attribute__((ext_vector_type(8))) short bf16x8;
typedef __attribute__((ext_vector_type(4))) float f32x4;

#define MFMA16(a, b, c) __builtin_amdgcn_mfma_f32_16x16x32_bf16(a, b, c, 0, 0, 0)

__device__ __forceinline__ unsigned short f2bf(float f) {
  unsigned u = __float_as_uint(f);
  u += 0x7fff + ((u >> 16) & 1);
  return (unsigned short)(u >> 16);
}

__device__ __forceinline__ void async16(void* l, const void* g) {
  __builtin_amdgcn_global_load_lds(
      (const __attribute__((address_space(1))) unsigned int*)g,
      (__attribute__((address_space(3))) unsigned int*)l, 16, 0, 0);
}

// ---------------- sim_matrix column inverse norms ----------------
__global__ void simnorm_kernel(const float* __restrict__ sm, float* __restrict__ inv_smn) {
  __shared__ float red[16][17];
  int t = threadIdx.x;
  int e = t & 15, g = t >> 4;
  float ss = 0.f;
  for (int c = g; c < HID; c += 16) {
    float v = sm[c * NEXP + e];
    ss += v * v;
  }
  red[e][g] = ss;
  __syncthreads();
  if (t < 16) {
    float s = 0.f;
    #pragma unroll
    for (int i = 0; i < 16; i++) s += red[t][i];
    inv_smn[t] = 1.f / fmaxf(sqrtf(s), 1e-12f);
  }
}

// ---------------- gate: scores, k, routing weights, bf16 cast of x ----------------
__global__ __launch_bounds__(256)
void gate_kernel(const float* __restrict__ x, const float* __restrict__ sm,
                 const float* __restrict__ thr, const float* __restrict__ inv_smn,
                 float* __restrict__ scores_out, float* __restrict__ k_out,
                 float* __restrict__ rw_out, unsigned short* __restrict__ xb_out) {
  const int n = blockIdx.x;
  const int t = threadIdx.x;
  const int lane = t & 63, wave = t >> 6;
  const float* xr = x + (size_t)n * HID;

  float p[16];
  #pragma unroll
  for (int e = 0; e < 16; e++) p[e] = 0.f;
  float ss = 0.f;

  #pragma unroll
  for (int q = 0; q < 4; q++) {
    int c = t + q * 256;
    float v = xr[c];
    ss += v * v;
    xb_out[(size_t)n * HID + c] = f2bf(v);
    const float4* smr = (const float4*)(sm + (size_t)c * NEXP);
    float4 s0 = smr[0], s1 = smr[1], s2 = smr[2], s3 = smr[3];
    p[0] += v * s0.x;  p[1] += v * s0.y;  p[2] += v * s0.z;  p[3] += v * s0.w;
    p[4] += v * s1.x;  p[5] += v * s1.y;  p[6] += v * s1.z;  p[7] += v * s1.w;
    p[8] += v * s2.x;  p[9] += v * s2.y;  p[10] += v * s2.z; p[11] += v * s2.w;
    p[12] += v * s3.x; p[13] += v * s3.y; p[14] += v * s3.z; p[15] += v * s3.w;
  }

  #pragma unroll
  for (int off = 32; off > 0; off >>= 1) {
    ss += __shfl_down(ss, off, 64);
    #pragma unroll
    for (int e = 0; e < 16; e++) p[e] += __shfl_down(p[e], off, 64);
  }

  __shared__ float red[4][17];
  __shared__ float sc[16];
  if (lane == 0) {
    red[wave][0] = ss;
    #pragma unroll
    for (int e = 0; e < 16; e++) red[wave][1 + e] = p[e];
  }
  __syncthreads();

  if (t < 16) {
    float d = red[0][1 + t] + red[1][1 + t] + red[2][1 + t] + red[3][1 + t];
    float ssum = red[0][0] + red[1][0] + red[2][0] + red[3][0];
    float inv_x = 1.f / fmaxf(sqrtf(ssum), 1e-12f);
    float s = d * inv_x * inv_smn[t];
    scores_out[(size_t)n * 16 + t] = s;
    sc[t] = s;
  }
  __syncthreads();

  if (t < 16) {
    float thrv = thr[0];
    float s = sc[t];
    bool act = s > thrv;
    float m = act ? s : -INFINITY;
    int cnt = act ? 1 : 0;
    #pragma unroll
    for (int off = 8; off > 0; off >>= 1) {
      m = fmaxf(m, __shfl_xor(m, off, 16));
      cnt += __shfl_xor(cnt, off, 16);
    }
    float pv;
    if (cnt > 0) pv = act ? expf(s - m) : 0.f;
    else         pv = 1.f;
    float sum = pv;
    #pragma unroll
    for (int off = 8; off > 0; off >>= 1) sum += __shfl_xor(sum, off, 16);
    rw_out[(size_t)n * 16 + t] = pv / sum;
    if (t == 0) k_out[n] = (float)cnt;
  }
}

// ---------------- transpose + bf16 cast (per-expert 2D transpose) ----------------
__global__ __launch_bounds__(256)
void transpose_cast_kernel(const float* __restrict__ src, unsigned short* __restrict__ dst,
                           int R, int C, int dstride, int e_src_stride, int e_dst_mult) {
  __shared__ float tile[32][33];
  const int e = blockIdx.z;
  const int r0 = blockIdx.y * 32, c0 = blockIdx.x * 32;
  const int tx = threadIdx.x & 31, ty = threadIdx.x >> 5;
  const float* s = src + (size_t)e * e_src_stride;
  #pragma unroll
  for (int q = 0; q < 4; q++) {
    int r = r0 + ty + q * 8;
    tile[ty + q * 8][tx] = s[(size_t)r * C + c0 + tx];
  }
  __syncthreads();
  unsigned short* d = dst + (size_t)e * e_dst_mult;
  #pragma unroll
  for (int q = 0; q < 4; q++) {
    int cc = c0 + ty + q * 8;
    int r  = r0 + tx;
    d[(size_t)cc * dstride + r] = f2bf(tile[tx][ty + q * 8]);
  }
}

// ======= GEMM1: 256x256, BK=64, 8 waves, SINGLE-buffer, 2 blocks/CU =======
// r7-verified structure; launch bounds fixed (512,2) so acc stays in regs
// (r7's (512,4) forced a 64-VGPR budget -> spill -> 513MB FETCH).
// Per tile: {8 gload_lds; __syncthreads; 24 ds_read + 64 MFMA plain
// (compiler-scheduled); __syncthreads}. Cross-BLOCK overlap (2/CU, no mutual
// barriers) hides stage drains. LDS 64 KiB: A [256r][128B] @0, B @32768.
// Swizzle byte^=(r&7)<<4 via pre-swizzled global source + same XOR on reads.
template <int KEXT, int LD, int NBN>
__global__ __launch_bounds__(512, 2)
void gemm1_k(const unsigned short* __restrict__ A, const unsigned short* __restrict__ B,
             unsigned short* __restrict__ Cb, const float* __restrict__ rw) {
  __shared__ __align__(1024) char lds[65536];
  constexpr int NT = KEXT / 64;
  const int tid = threadIdx.x;
  const int lane = tid & 63, wid = tid >> 6;
  const int wm = wid >> 2, wn = wid & 3;   // 2 x 4 waves, wave tile 128x64
  const int lr = lane & 15;

  const int nwg = gridDim.x, cpx = nwg >> 3;
  const int wg = (blockIdx.x & 7) * cpx + (blockIdx.x >> 3);
  const int bm = wg / NBN, bn = wg % NBN;

  const int swz = (lr & 7) << 4;
  const int colk0 = ((lane >> 4) * 16) ^ swz;
  const int colk1 = (64 + (lane >> 4) * 16) ^ swz;
  const int wmo = wm * 16384, wno = wn * 8192, lro = lr * 128;

  // staging decode: A/B tiles [256 r][128 B]; 4 units x 512 thr x 16 B each
  int sRow[4], sCol[4], so[4];
  #pragma unroll
  for (int i = 0; i < 4; i++) {
    int o = (i * 512 + tid) * 16;
    so[i] = o;
    int r = o >> 7, cb = o & 127;
    sRow[i] = r; sCol[i] = (cb ^ ((r & 7) << 4)) >> 1;
  }

  const unsigned short* Ag = A + (size_t)bm * 256 * LD;
  const unsigned short* Bg = B + (size_t)bn * 256 * LD;

  f32x4 acc[8][4];
  #pragma unroll
  for (int m = 0; m < 8; m++)
    #pragma unroll
    for (int n = 0; n < 4; n++) acc[m][n] = (f32x4){0.f, 0.f, 0.f, 0.f};

  #pragma unroll 1
  for (int t = 0; t < NT; ++t) {
    const int kt = t * 64;
    #pragma unroll
    for (int i = 0; i < 4; i++) {
      async16(lds + so[i],         Ag + (size_t)sRow[i] * LD + kt + sCol[i]);
      async16(lds + 32768 + so[i], Bg + (size_t)sRow[i] * LD + kt + sCol[i]);
    }
    __syncthreads();   // drains vmcnt (gload_lds) + barrier

    // kk = 0
    {
      bf16x8 a[8], b[4];
      #pragma unroll
      for (int mf = 0; mf < 8; mf++)
        a[mf] = *(const bf16x8*)(lds + wmo + mf * 2048 + lro + colk0);
      #pragma unroll
      for (int nf = 0; nf < 4; nf++)
        b[nf] = *(const bf16x8*)(lds + 32768 + wno + nf * 2048 + lro + colk0);
      #pragma unroll
      for (int mf = 0; mf < 8; mf++)
        #pragma unroll
        for (int nf = 0; nf < 4; nf++)
          acc[mf][nf] = MFMA16(a[mf], b[nf], acc[mf][nf]);
    }
    // kk = 1
    {
      bf16x8 a[8], b[4];
      #pragma unroll
      for (int mf = 0; mf < 8; mf++)
        a[mf] = *(const bf16x8*)(lds + wmo + mf * 2048 + lro + colk1);
      #pragma unroll
      for (int nf = 0; nf < 4; nf++)
        b[nf] = *(const bf16x8*)(lds + 32768 + wno + nf * 2048 + lro + colk1);
      #pragma unroll
      for (int mf = 0; mf < 8; mf++)
        #pragma unroll
        for (int nf = 0; nf < 4; nf++)
          acc[mf][nf] = MFMA16(a[mf], b[nf], acc[mf][nf]);
    }
    __syncthreads();   // write-after-read protection for next stage
  }

  // epilogue: C/D layout col=lane&15, row=(lane>>4)*4+j
  const int jr = (lane >> 4) * 4;
  float wrow[8][4];
  #pragma unroll
  for (int m = 0; m < 8; m++)
    #pragma unroll
    for (int j = 0; j < 4; j++)
      wrow[m][j] = rw[(size_t)(bm * 256 + wm * 128 + m * 16 + jr + j) * 16 + bn];
  #pragma unroll
  for (int m = 0; m < 8; m++) {
    #pragma unroll
    for (int n = 0; n < 4; n++) {
      int col = bn * 256 + wn * 64 + n * 16 + lr;
      #pragma unroll
      for (int j = 0; j < 4; j++) {
        int r = bm * 256 + wm * 128 + m * 16 + jr + j;
        float v = acc[m][n][j];
        float g = 0.7978845608f * (v + 0.044715f * v * v * v);
        float e = __expf(2.f * g);
        float th = 1.f - 2.f / (e + 1.f);   // tanh(g), inf-safe
        float ge = 0.5f * v * (1.f + th);
        Cb[(size_t)r * NBIG + col] = f2bf(ge * wrow[m][j]);
      }
    }
  }
}

// ============ GEMM2: 128x256, 8-wave (2x4), 2-phase/K-tile (r6-verified) ============
#define G2PHASE(CK, STG, WAIT_)                                                \
  {                                                                            \
    bf16x8 afr[4], bfr[4];                                                     \
    _Pragma("unroll")                                                          \
    for (int ml = 0; ml < 4; ml++)                                             \
      afr[ml] = *(const bf16x8*)(bufA + wmo + ml*2048 + lro + (CK));           \
    _Pragma("unroll")                                                          \
    for (int nl = 0; nl < 4; nl++)                                             \
      bfr[nl] = *(const bf16x8*)(bufB + wno + nl*2048 + lro + (CK));           \
    if (STG) {                                                                 \
      _Pragma("unroll")                                                        \
      for (int i = 0; i < 2; i++)                                              \
        async16(ldsAn + o16[i], Ag + (size_t)aRow[i]*K + kn + aCol[i]);        \
      _Pragma("unroll")                                                        \
      for (int i = 0; i < 4; i++)                                              \
        async16(ldsBn + o16b[i], Bg + (size_t)bRow[i]*K + kn + bCol[i]);       \
    }                                                                          \
    __builtin_amdgcn_sched_barrier(0);                                         \
    __builtin_amdgcn_s_barrier();                                              \
    asm volatile("s_waitcnt lgkmcnt(0)" ::: "memory");                         \
    __builtin_amdgcn_sched_barrier(0);                                         \
    __builtin_amdgcn_s_setprio(1);                                             \
    _Pragma("unroll")                                                          \
    for (int m4 = 0; m4 < 4; m4++)                                             \
      _Pragma("unroll")                                                        \
      for (int n4 = 0; n4 < 4; n4++)                                           \
        acc[m4][n4] = MFMA16(afr[m4], bfr[n4], acc[m4][n4]);                   \
    __builtin_amdgcn_s_setprio(0);                                             \
    __builtin_amdgcn_sched_barrier(0);                                         \
    if (WAIT_) { asm volatile("s_waitcnt vmcnt(0)" ::: "memory"); }            \
    __builtin_amdgcn_s_barrier();                                              \
    __builtin_amdgcn_sched_barrier(0);                                         \
  }

template <int K>
__global__ __launch_bounds__(512, 2)
void gemm2_k(const unsigned short* __restrict__ A, const unsigned short* __restrict__ B,
             float* __restrict__ Cf) {
  __shared__ __align__(1024) char lds[98304];
  constexpr int NT = K / 64;
  const int tid = threadIdx.x;
  const int lane = tid & 63, wid = tid >> 6;
  const int wm = wid >> 2, wn = wid & 3;   // 2 x 4 waves, wave tile 64x64
  const int lr = lane & 15;

  const int wg = (blockIdx.x & 7) * 32 + (blockIdx.x >> 3);  // nwg=256
  const int bm = wg >> 2, bn = wg & 3;

  const int swz = (lr & 7) << 4;
  const int colk0 = ((lane >> 4) * 16) ^ swz;
  const int colk1 = (64 + (lane >> 4) * 16) ^ swz;
  const int wmo = wm * 8192, wno = wn * 8192, lro = lr * 128;

  int aRow[2], aCol[2], o16[2];
  int bRow[4], bCol[4], o16b[4];
  #pragma unroll
  for (int i = 0; i < 2; i++) {
    int o = (i * 512 + tid) * 16;
    o16[i] = o;
    int r = o >> 7, cb = o & 127;
    aRow[i] = r; aCol[i] = (cb ^ ((r & 7) << 4)) >> 1;
  }
  #pragma unroll
  for (int i = 0; i < 4; i++) {
    int o = (i * 512 + tid) * 16;
    o16b[i] = o;
    int r = o >> 7, cb = o & 127;
    bRow[i] = r; bCol[i] = (cb ^ ((r & 7) << 4)) >> 1;
  }

  const unsigned short* Ag = A + (size_t)bm * 128 * K;
  const unsigned short* Bg = B + (size_t)bn * 256 * K;

  f32x4 acc[4][4];
  #pragma unroll
  for (int m = 0; m < 4; m++)
    #pragma unroll
    for (int n = 0; n < 4; n++) acc[m][n] = (f32x4){0.f, 0.f, 0.f, 0.f};

  #pragma unroll
  for (int i = 0; i < 2; i++) async16(lds + o16[i],          Ag + (size_t)aRow[i] * K + aCol[i]);
  #pragma unroll
  for (int i = 0; i < 4; i++) async16(lds + 32768 + o16b[i], Bg + (size_t)bRow[i] * K + bCol[i]);
  asm volatile("s_waitcnt vmcnt(0)" ::: "memory");
  __builtin_amdgcn_s_barrier();

  #pragma unroll 1
  for (int t = 0; t < NT; t += 2) {
    {
      const char* bufA = lds;
      const char* bufB = lds + 32768;
      char* ldsAn = lds + 16384;
      char* ldsBn = lds + 32768 + 32768;
      const int kn = ((t + 1) & (NT - 1)) << 6;
      G2PHASE(colk0, 1, 0)
      G2PHASE(colk1, 0, 1)
    }
    {
      const char* bufA = lds + 16384;
      const char* bufB = lds + 32768 + 32768;
      char* ldsAn = lds;
      char* ldsBn = lds + 32768;
      const int kn = ((t + 2) & (NT - 1)) << 6;
      G2PHASE(colk0, 1, 0)
      G2PHASE(colk1, 0, 1)
    }
  }

  asm volatile("s_waitcnt vmcnt(0)" ::: "memory");

  const int jr = (lane >> 4) * 4;
  #pragma unroll
  for (int m = 0; m < 4; m++) {
    #pragma unroll
    for (int n = 0; n < 4; n++) {
      int col = bn * 256 + wn * 64 + n * 16 + lr;
      #pragma unroll
      for (int j = 0; j < 4; j++) {
        int r = bm * 128 + wm * 64 + m * 16 + jr + j;
        Cf[(size_t)r * HID + col] = acc[m][n][j];
      }
    }
  }
}

extern "C" void kernel_launch(void* const* d_in, const int* in_sizes, int n_in,
                              void* d_out, int out_size, void* d_ws, size_t ws_size,
                              hipStream_t stream) {
  const float* x   = (const float*)d_in[0];
  const float* sm  = (const float*)d_in[1];
  const float* thr = (const float*)d_in[2];
  const float* w1  = (const float*)d_in[3];
  const float* w2  = (const float*)d_in[4];

  float* out_final  = (float*)d_out;
  float* out_scores = out_final + (size_t)NTOK * HID;
  float* out_k      = out_scores + (size_t)NTOK * NEXP;

  char* ws = (char*)d_ws;
  size_t off = 0;
  float* inv_smn = (float*)(ws + off); off += 256;
  float* rwbuf   = (float*)(ws + off); off += (size_t)NTOK * NEXP * 4;
  unsigned short* Xb  = (unsigned short*)(ws + off); off += (size_t)NTOK * HID * 2;
  unsigned short* W1T = (unsigned short*)(ws + off); off += (size_t)NBIG * HID * 2;
  unsigned short* W2T = (unsigned short*)(ws + off); off += (size_t)HID * NBIG * 2;
  unsigned short* H   = (unsigned short*)(ws + off); off += (size_t)NTOK * NBIG * 2;

  simnorm_kernel<<<1, 256, 0, stream>>>(sm, inv_smn);
  gate_kernel<<<NTOK, 256, 0, stream>>>(x, sm, thr, inv_smn, out_scores, out_k, rwbuf, Xb);
  transpose_cast_kernel<<<dim3(ISZ / 32, HID / 32, NEXP), 256, 0, stream>>>(
      w1, W1T, HID, ISZ, HID, HID * ISZ, ISZ * HID);
  transpose_cast_kernel<<<dim3(HID / 32, ISZ / 32, NEXP), 256, 0, stream>>>(
      w2, W2T, ISZ, HID, NBIG, ISZ * HID, ISZ);

  // H = gelu(Xb @ W1T^T) * rw   [8192 x 4096], 512 blocks, single-buffer 2/CU
  gemm1_k<HID, HID, 16><<<512, 512, 0, stream>>>(Xb, W1T, H, rwbuf);
  // final = H @ W2T^T            [8192 x 1024], 256 blocks (r6-verified dbuf)
  gemm2_k<NBIG><<<256, 512, 0, stream>>>(H, W2T, out_final);
}